// Round 1
// baseline (105.612 us; speedup 1.0000x reference)
//
#include <hip/hip_runtime.h>
#include <math.h>

#define NB 32
#define NA 48
#define NSP 4
#define RCRc 5.2f
#define RCAc 3.5f
#define PI_F 3.14159265358979f

// One block per (batch, center-atom). 128 threads.
// Phase 1: per-j distances -> radial accumulation (LDS atomics) + RCA neighbor compaction.
// Phase 2: triple loop over compacted neighbors -> angular accumulation (LDS atomics).
// f1 = ((1+cos(theta - shf_z))/2)^32 computed via cos(theta-s)=cosT*cos s + sinT*sin s
// (theta in [0,pi] so sinT = sqrt(1-cosT^2) is exact) and x^32 by 5 squarings.
__global__ __launch_bounds__(128)
void aev_kernel(const int* __restrict__ species, const float* __restrict__ coords,
                float* __restrict__ out)
{
    const int bid = blockIdx.x;
    const int b = bid / NA;
    const int i = bid - b * NA;
    const int tid = threadIdx.x;
    const int bd = blockDim.x;

    __shared__ float sx[NA], sy[NA], szc[NA];
    __shared__ int   ssp[NA];
    __shared__ float rad[64];
    __shared__ float ang[320];
    __shared__ float ndx[NA], ndy[NA], ndz[NA], ndd[NA], nfc[NA];
    __shared__ int   nspn[NA];
    __shared__ int   cnt;

    if (tid < NA) {
        const float* cp = coords + ((size_t)(b * NA + tid)) * 3;
        sx[tid]  = cp[0];
        sy[tid]  = cp[1];
        szc[tid] = cp[2];
        ssp[tid] = species[b * NA + tid];
    }
    for (int f = tid; f < 64;  f += bd) rad[f] = 0.0f;
    for (int f = tid; f < 320; f += bd) ang[f] = 0.0f;
    if (tid == 0) cnt = 0;
    __syncthreads();

    const float xi = sx[i], yi = sy[i], zi = szc[i];

    // ---- Phase 1: radial + neighbor compaction ----
    if (tid < NA && tid != i) {
        const int j = tid;
        const float dx = sx[j] - xi, dy = sy[j] - yi, dz = szc[j] - zi;
        const float d = sqrtf(dx * dx + dy * dy + dz * dz);
        if (d <= RCRc) {
            const float fc = 0.5f * __cosf((PI_F / RCRc) * d) + 0.5f;
            const int s = ssp[j];
            #pragma unroll
            for (int r = 0; r < 16; ++r) {
                const float u = d - (0.9f + 0.26875f * (float)r);
                atomicAdd(&rad[s * 16 + r], 0.25f * __expf(-16.0f * u * u) * fc);
            }
        }
        if (d <= RCAc) {
            const float fca = 0.5f * __cosf((PI_F / RCAc) * d) + 0.5f;
            const int pos = atomicAdd(&cnt, 1);
            ndx[pos] = dx; ndy[pos] = dy; ndz[pos] = dz;
            ndd[pos] = d;  nfc[pos] = fca; nspn[pos] = ssp[j];
        }
    }
    __syncthreads();

    const int m = cnt;
    const int T = m * (m - 1) / 2;

    // cos/sin of SHF_Z[z] = (2z+1)*pi/16
    const float CZ[8] = { 0.98078528f, 0.83146961f, 0.55557023f, 0.19509032f,
                         -0.19509032f,-0.55557023f,-0.83146961f,-0.98078528f };
    const float SZ[8] = { 0.19509032f, 0.55557023f, 0.83146961f, 0.98078528f,
                          0.98078528f, 0.83146961f, 0.55557023f, 0.19509032f };
    const float SA[4] = { 0.9f, 1.55f, 2.2f, 2.85f };

    // ---- Phase 2: angular triples (j < k among compacted neighbors) ----
    for (int t = tid; t < T; t += bd) {
        int jj = 0, rem = t;
        while (rem >= m - 1 - jj) { rem -= m - 1 - jj; ++jj; }
        const int kk = jj + 1 + rem;

        const float djx = ndx[jj], djy = ndy[jj], djz = ndz[jj];
        const float dkx = ndx[kk], dky = ndy[kk], dkz = ndz[kk];
        const float dj = ndd[jj], dk = ndd[kk];
        const float dot = djx * dkx + djy * dky + djz * dkz;
        const float cosT = 0.95f * dot / (dj * dk);
        const float sinT = sqrtf(fmaxf(1.0f - cosT * cosT, 0.0f));
        const float avg = 0.5f * (dj + dk);
        const float w = 2.0f * nfc[jj] * nfc[kk];

        const int s1 = nspn[jj], s2 = nspn[kk];
        const int lo = min(s1, s2), hi = max(s1, s2);
        const int p = (lo * (9 - lo)) / 2 + (hi - lo);  // PAIR_IDX[s1,s2]

        float f1v[8];
        #pragma unroll
        for (int z = 0; z < 8; ++z) {
            const float base = 0.5f + 0.5f * (cosT * CZ[z] + sinT * SZ[z]);
            const float b2 = base * base;
            const float b4 = b2 * b2;
            const float b8 = b4 * b4;
            const float b16 = b8 * b8;
            f1v[z] = b16 * b16;  // base^32
        }
        float* ap = &ang[p * 32];
        #pragma unroll
        for (int a = 0; a < 4; ++a) {
            const float u = avg - SA[a];
            const float wf2 = w * __expf(-8.0f * u * u);
            #pragma unroll
            for (int z = 0; z < 8; ++z) {
                atomicAdd(&ap[a * 8 + z], wf2 * f1v[z]);
            }
        }
    }
    __syncthreads();

    // ---- Write out ----
    float* op = out + (NB * NA) + ((size_t)(b * NA + i)) * 384;
    for (int f = tid; f < 64;  f += bd) op[f] = rad[f];
    for (int f = tid; f < 320; f += bd) op[64 + f] = ang[f];
    if (tid == 0) out[b * NA + i] = (float)ssp[i];  // species as float values
}

extern "C" void kernel_launch(void* const* d_in, const int* in_sizes, int n_in,
                              void* d_out, int out_size, void* d_ws, size_t ws_size,
                              hipStream_t stream) {
    const int*   species = (const int*)d_in[0];
    const float* coords  = (const float*)d_in[1];
    float*       out     = (float*)d_out;
    aev_kernel<<<NB * NA, 128, 0, stream>>>(species, coords, out);
}

// Round 2
// 67.213 us; speedup vs baseline: 1.5713x; 1.5713x over previous
//
#include <hip/hip_runtime.h>
#include <math.h>

#define NB 32
#define NA 48
#define RCRf 5.2f
#define RCAf 3.5f
#define PI_F 3.14159265358979f
#define CMAX 384   // triple records per chunk (worst case T = C(47,2)=1081 -> 3 chunks)

// One block per (batch, center atom). 320 threads = 5 waves.
// No float atomics anywhere:
//  - pair pass: wave 0, ballot-compacted RCA neighbor list
//  - radial: 64 feature-owner threads x 5 j-segments, register accumulate
//  - angular: triples bucketed by pair index p (int histogram + prefix),
//             per-triple records (f1[8], w*f2[4]) in LDS, then 320
//             feature-owner threads scan only their own p-bucket.
__global__ __launch_bounds__(320)
void aev_kernel(const int* __restrict__ species, const float* __restrict__ coords,
                float* __restrict__ out)
{
    const int bid = blockIdx.x;
    const int b = bid / NA;
    const int i = bid - b * NA;
    const int tid = threadIdx.x;

    __shared__ float crd[NA * 3];
    __shared__ int   ssp[NA];
    __shared__ float pd[NA], pfr[NA];
    __shared__ float cdx[NA], cdy[NA], cdz[NA], cdd[NA], cfc[NA];
    __shared__ int   csp[NA];
    __shared__ int   sm;
    __shared__ float radpart[5 * 64];
    __shared__ float f1rec[CMAX * 8];
    __shared__ float w2rec[CMAX * 4];
    __shared__ int   cnt[10], basep[10];
    __shared__ unsigned cur[10];

    // ---- load batch coords + species (coalesced) ----
    if (tid < NA * 3) crd[tid] = coords[(size_t)b * NA * 3 + tid];
    if (tid >= 192 && tid < 192 + NA) ssp[tid - 192] = species[b * NA + (tid - 192)];
    __syncthreads();

    const float xi = crd[3 * i], yi = crd[3 * i + 1], zi = crd[3 * i + 2];

    // ---- pair pass (wave 0 only): distances, radial fc, RCA compaction ----
    if (tid < 64) {
        const int j = tid;
        float dx = 0.f, dy = 0.f, dz = 0.f, d = 1.0f, fr = 0.0f, fa = 0.0f;
        bool inA = false;
        if (j < NA) {
            dx = crd[3 * j] - xi; dy = crd[3 * j + 1] - yi; dz = crd[3 * j + 2] - zi;
            d = sqrtf(dx * dx + dy * dy + dz * dz);
            if (j != i && d <= RCRf) fr = 0.5f * __cosf((PI_F / RCRf) * d) + 0.5f;
            if (j != i && d <= RCAf) { inA = true; fa = 0.5f * __cosf((PI_F / RCAf) * d) + 0.5f; }
            pd[j] = d; pfr[j] = fr;
        }
        const unsigned long long mask = __ballot(inA);
        if (inA) {
            const int pos = (int)__popcll(mask & ((1ull << j) - 1ull));
            cdx[pos] = dx; cdy[pos] = dy; cdz[pos] = dz;
            cdd[pos] = d;  cfc[pos] = fa; csp[pos] = ssp[j];
        }
        if (j == 0) sm = (int)__popcll(mask);
    }
    __syncthreads();

    // ---- radial: feature-owner accumulation (all LDS reads are broadcasts) ----
    {
        const int f = tid & 63, seg = tid >> 6;
        const int s = f >> 4, r = f & 15;
        const float shf = 0.9f + 0.26875f * (float)r;
        float acc = 0.0f;
        const int j0 = seg * 10, j1 = min(NA, j0 + 10);
        for (int j = j0; j < j1; ++j) {
            const float fr = pfr[j];          // wave-uniform broadcast
            if (fr != 0.0f) {                 // uniform skip
                const float u = pd[j] - shf;
                const float v = 0.25f * __expf(-16.0f * u * u) * fr;
                acc += (ssp[j] == s) ? v : 0.0f;
            }
        }
        radpart[seg * 64 + f] = acc;
    }

    const int m = sm;
    const int T = m * (m - 1) / 2;
    const int nchunks = (T + CMAX - 1) / CMAX;

    const float CZ[8] = { 0.98078528f, 0.83146961f, 0.55557023f, 0.19509032f,
                         -0.19509032f,-0.55557023f,-0.83146961f,-0.98078528f };
    const float SZ[8] = { 0.19509032f, 0.55557023f, 0.83146961f, 0.98078528f,
                          0.98078528f, 0.83146961f, 0.55557023f, 0.19509032f };
    const float SA[4] = { 0.9f, 1.55f, 2.2f, 2.85f };

    const int pmine = tid >> 5, amine = (tid >> 3) & 3, zmine = tid & 7;
    float acc_a = 0.0f;

    for (int c = 0; c < nchunks; ++c) {
        const int t0 = c * CMAX;
        const int cT = min(CMAX, T - t0);
        __syncthreads();
        if (tid < 10) cnt[tid] = 0;
        __syncthreads();

        // pass A: histogram of pair indices (cheap int atomics on 10 addrs)
        for (int t = tid; t < cT; t += 320) {
            const int g = t0 + t;
            int jj = 0, rem = g;
            while (rem >= m - 1 - jj) { rem -= m - 1 - jj; ++jj; }
            const int kk = jj + 1 + rem;
            const int s1 = csp[jj], s2 = csp[kk];
            const int lo = min(s1, s2), hi = max(s1, s2);
            const int p = (lo * (9 - lo)) / 2 + (hi - lo);
            atomicAdd(&cnt[p], 1);
        }
        __syncthreads();
        if (tid == 0) {
            int run = 0;
            for (int p = 0; p < 10; ++p) { basep[p] = run; cur[p] = (unsigned)run; run += cnt[p]; }
        }
        __syncthreads();

        // pass B: compute triple records, place into p-sorted slots
        for (int t = tid; t < cT; t += 320) {
            const int g = t0 + t;
            int jj = 0, rem = g;
            while (rem >= m - 1 - jj) { rem -= m - 1 - jj; ++jj; }
            const int kk = jj + 1 + rem;

            const float djx = cdx[jj], djy = cdy[jj], djz = cdz[jj];
            const float dkx = cdx[kk], dky = cdy[kk], dkz = cdz[kk];
            const float dj = cdd[jj], dk = cdd[kk];
            const float dot = djx * dkx + djy * dky + djz * dkz;
            const float cosT = 0.95f * dot / (dj * dk);
            const float sinT = sqrtf(fmaxf(1.0f - cosT * cosT, 0.0f));
            const float avg = 0.5f * (dj + dk);
            const float w = 2.0f * cfc[jj] * cfc[kk];
            const int s1 = csp[jj], s2 = csp[kk];
            const int lo = min(s1, s2), hi = max(s1, s2);
            const int p = (lo * (9 - lo)) / 2 + (hi - lo);

            float f1v[8];
            #pragma unroll
            for (int z = 0; z < 8; ++z) {
                const float base = 0.5f + 0.5f * (cosT * CZ[z] + sinT * SZ[z]);
                const float b2 = base * base, b4 = b2 * b2, b8 = b4 * b4, b16 = b8 * b8;
                f1v[z] = b16 * b16;   // base^32
            }
            float w2v[4];
            #pragma unroll
            for (int a = 0; a < 4; ++a) {
                const float u = avg - SA[a];
                w2v[a] = w * __expf(-8.0f * u * u);
            }
            const unsigned pos = atomicAdd(&cur[p], 1u);
            ((float4*)f1rec)[pos * 2]     = make_float4(f1v[0], f1v[1], f1v[2], f1v[3]);
            ((float4*)f1rec)[pos * 2 + 1] = make_float4(f1v[4], f1v[5], f1v[6], f1v[7]);
            ((float4*)w2rec)[pos]         = make_float4(w2v[0], w2v[1], w2v[2], w2v[3]);
        }
        __syncthreads();

        // stage C: each thread scans only its own p-bucket
        {
            const int klo = basep[pmine];
            const int khi = klo + cnt[pmine];
            for (int k = klo; k < khi; ++k)
                acc_a += w2rec[k * 4 + amine] * f1rec[k * 8 + zmine];
        }
    }
    __syncthreads();   // protects radpart reads below when nchunks==0, and cnt reuse

    // ---- output ----
    float* op = out + NB * NA + (size_t)(b * NA + i) * 384;
    if (tid < 64) {
        op[tid] = radpart[tid] + radpart[64 + tid] + radpart[128 + tid] +
                  radpart[192 + tid] + radpart[256 + tid];
    }
    op[64 + tid] = acc_a;
    if (tid == 0) out[b * NA + i] = (float)ssp[i];
}

extern "C" void kernel_launch(void* const* d_in, const int* in_sizes, int n_in,
                              void* d_out, int out_size, void* d_ws, size_t ws_size,
                              hipStream_t stream) {
    const int*   species = (const int*)d_in[0];
    const float* coords  = (const float*)d_in[1];
    float*       out     = (float*)d_out;
    aev_kernel<<<NB * NA, 320, 0, stream>>>(species, coords, out);
}

// Round 3
// 66.486 us; speedup vs baseline: 1.5885x; 1.0109x over previous
//
#include <hip/hip_runtime.h>
#include <math.h>

#define NB 32
#define NA 48
#define RCRf 5.2f
#define RCAf 3.5f
#define PI_F 3.14159265358979f
#define CMAX 384   // triple records per chunk (worst case T = C(47,2)=1081 -> 3 chunks)

// One block per (batch, center atom). 320 threads = 5 waves, 6 blocks/CU -> all
// 1536 blocks co-resident (256 CU x 6 = 1536).
// vs R2: no serial tid0 prefix (all-thread redundant register prefix over 10
// broadcast LDS reads), closed-form triangular decode (no divergent while),
// decode done ONCE (packed jj|kk|p cached in LDS), 5 barriers on the hot path.
__device__ inline void tri_decode(int t, int m, int T, int& jj, int& kk) {
    const int u = T - 1 - t;                     // reverse index
    int r = (int)((sqrtf(8.0f * (float)u + 1.0f) - 1.0f) * 0.5f);
    while (r * (r + 1) / 2 > u) --r;             // fixup (<=1 iter)
    while ((r + 1) * (r + 2) / 2 <= u) ++r;
    jj = m - 2 - r;
    kk = m - 1 - (u - r * (r + 1) / 2);
}

__global__ __launch_bounds__(320)
void aev_kernel(const int* __restrict__ species, const float* __restrict__ coords,
                float* __restrict__ out)
{
    const int bid = blockIdx.x;
    const int b = bid / NA;
    const int i = bid - b * NA;
    const int tid = threadIdx.x;

    __shared__ float crd[NA * 3];
    __shared__ int   ssp[NA];
    __shared__ float pd[NA], pfr[NA];
    __shared__ float cdx[NA], cdy[NA], cdz[NA], cdd[NA], cfc[NA];
    __shared__ int   csp[NA];
    __shared__ int   sm;
    __shared__ float radpart[5 * 64];
    __shared__ __align__(16) float f1rec[CMAX * 8];
    __shared__ __align__(16) float w2rec[CMAX * 4];
    __shared__ int   trec[CMAX];        // packed jj | kk<<6 | p<<12
    __shared__ int   cnt[10];
    __shared__ unsigned cur[10];

    // ---- load batch coords + species, zero chunk-0 histogram ----
    if (tid < NA * 3) crd[tid] = coords[(size_t)b * NA * 3 + tid];
    if (tid >= 192 && tid < 192 + NA) ssp[tid - 192] = species[b * NA + (tid - 192)];
    if (tid >= 256 && tid < 266) cnt[tid - 256] = 0;
    __syncthreads();                                                  // S1

    const float xi = crd[3 * i], yi = crd[3 * i + 1], zi = crd[3 * i + 2];

    // ---- pair pass (wave 0): distances, radial fc, ballot-compacted RCA list ----
    if (tid < 64) {
        const int j = tid;
        float dx = 0.f, dy = 0.f, dz = 0.f, d = 1.0f, fr = 0.0f, fa = 0.0f;
        bool inA = false;
        if (j < NA) {
            dx = crd[3 * j] - xi; dy = crd[3 * j + 1] - yi; dz = crd[3 * j + 2] - zi;
            d = sqrtf(dx * dx + dy * dy + dz * dz);
            if (j != i && d <= RCRf) fr = 0.5f * __cosf((PI_F / RCRf) * d) + 0.5f;
            if (j != i && d <= RCAf) { inA = true; fa = 0.5f * __cosf((PI_F / RCAf) * d) + 0.5f; }
            pd[j] = d; pfr[j] = fr;
        }
        const unsigned long long mask = __ballot(inA);
        if (inA) {
            const int pos = (int)__popcll(mask & ((1ull << j) - 1ull));
            cdx[pos] = dx; cdy[pos] = dy; cdz[pos] = dz;
            cdd[pos] = d;  cfc[pos] = fa; csp[pos] = ssp[j];
        }
        if (j == 0) sm = (int)__popcll(mask);
    }
    __syncthreads();                                                  // S2

    const int m = sm;
    const int T = m * (m - 1) / 2;
    const int nchunks = (T + CMAX - 1) / CMAX;

    // ---- radial (all waves, register acc) + chunk-0 histogram/decode ----
    {
        const int f = tid & 63, seg = tid >> 6;
        const int s = f >> 4, r = f & 15;
        const float shf = 0.9f + 0.26875f * (float)r;
        float acc = 0.0f;
        const int j0 = seg * 10, j1 = min(NA, j0 + 10);
        for (int j = j0; j < j1; ++j) {
            const float fr = pfr[j];              // wave-uniform broadcast
            if (fr != 0.0f) {
                const float u = pd[j] - shf;
                const float v = 0.25f * __expf(-16.0f * u * u) * fr;
                acc += (ssp[j] == s) ? v : 0.0f;
            }
        }
        radpart[seg * 64 + f] = acc;
    }
    {   // histogram + decode cache for chunk 0
        const int cT = min(CMAX, T);
        for (int t = tid; t < cT; t += 320) {
            int jj, kk; tri_decode(t, m, T, jj, kk);
            const int s1 = csp[jj], s2 = csp[kk];
            const int lo = min(s1, s2), hi = max(s1, s2);
            const int p = (lo * (9 - lo)) / 2 + (hi - lo);
            trec[t] = jj | (kk << 6) | (p << 12);
            atomicAdd(&cnt[p], 1);
        }
    }
    __syncthreads();                                                  // S3

    const float CZ[8] = { 0.98078528f, 0.83146961f, 0.55557023f, 0.19509032f,
                         -0.19509032f,-0.55557023f,-0.83146961f,-0.98078528f };
    const float SZ[8] = { 0.19509032f, 0.55557023f, 0.83146961f, 0.98078528f,
                          0.98078528f, 0.83146961f, 0.55557023f, 0.19509032f };
    const float SA[4] = { 0.9f, 1.55f, 2.2f, 2.85f };

    const int pmine = tid >> 5, amine = (tid >> 3) & 3, zmine = tid & 7;
    float acc_a = 0.0f;

    for (int c = 0; c < nchunks; ++c) {
        const int t0 = c * CMAX;
        const int cT = min(CMAX, T - t0);

        // all-thread redundant prefix over 10 broadcast reads (no serial phase)
        int mybase = 0, mycnt = 0, run = 0;
        #pragma unroll
        for (int p = 0; p < 10; ++p) {
            const int cp = cnt[p];
            if (p == pmine) { mybase = run; mycnt = cp; }
            if (tid < 10 && p == tid) cur[tid] = (unsigned)run;
            run += cp;
        }
        __syncthreads();                                              // S4

        // compute pass: records placed into p-sorted slots
        for (int t = tid; t < cT; t += 320) {
            const int pk = trec[t];
            const int jj = pk & 63, kk = (pk >> 6) & 63, p = pk >> 12;

            const float djx = cdx[jj], djy = cdy[jj], djz = cdz[jj];
            const float dkx = cdx[kk], dky = cdy[kk], dkz = cdz[kk];
            const float dj = cdd[jj], dk = cdd[kk];
            const float dot = djx * dkx + djy * dky + djz * dkz;
            const float cosT = 0.95f * dot * __frcp_rn(dj * dk);
            const float sinT = sqrtf(fmaxf(1.0f - cosT * cosT, 0.0f));
            const float avg = 0.5f * (dj + dk);
            const float w = 2.0f * cfc[jj] * cfc[kk];

            float f1v[8];
            #pragma unroll
            for (int z = 0; z < 8; ++z) {
                const float base = 0.5f + 0.5f * (cosT * CZ[z] + sinT * SZ[z]);
                const float b2 = base * base, b4 = b2 * b2, b8 = b4 * b4, b16 = b8 * b8;
                f1v[z] = b16 * b16;   // base^32
            }
            float w2v[4];
            #pragma unroll
            for (int a = 0; a < 4; ++a) {
                const float u = avg - SA[a];
                w2v[a] = w * __expf(-8.0f * u * u);
            }
            const unsigned pos = atomicAdd(&cur[p], 1u);
            ((float4*)f1rec)[pos * 2]     = make_float4(f1v[0], f1v[1], f1v[2], f1v[3]);
            ((float4*)f1rec)[pos * 2 + 1] = make_float4(f1v[4], f1v[5], f1v[6], f1v[7]);
            ((float4*)w2rec)[pos]         = make_float4(w2v[0], w2v[1], w2v[2], w2v[3]);
        }
        __syncthreads();                                              // S5

        // reduce: each thread scans only its own p-bucket (conflict-free)
        for (int k = mybase; k < mybase + mycnt; ++k)
            acc_a += w2rec[k * 4 + amine] * f1rec[k * 8 + zmine];

        // prep next chunk (rare: only when T > 384)
        if (c + 1 < nchunks) {
            __syncthreads();
            if (tid < 10) cnt[tid] = 0;
            __syncthreads();
            const int n0 = (c + 1) * CMAX;
            const int nT = min(CMAX, T - n0);
            for (int t = tid; t < nT; t += 320) {
                int jj, kk; tri_decode(n0 + t, m, T, jj, kk);
                const int s1 = csp[jj], s2 = csp[kk];
                const int lo = min(s1, s2), hi = max(s1, s2);
                const int p = (lo * (9 - lo)) / 2 + (hi - lo);
                trec[t] = jj | (kk << 6) | (p << 12);
                atomicAdd(&cnt[p], 1);
            }
            __syncthreads();
        }
    }

    // ---- output (radpart fenced by S3; acc_a is a register) ----
    float* op = out + NB * NA + (size_t)(b * NA + i) * 384;
    if (tid < 64) {
        op[tid] = radpart[tid] + radpart[64 + tid] + radpart[128 + tid] +
                  radpart[192 + tid] + radpart[256 + tid];
    }
    op[64 + tid] = acc_a;
    if (tid == 0) out[b * NA + i] = (float)ssp[i];
}

extern "C" void kernel_launch(void* const* d_in, const int* in_sizes, int n_in,
                              void* d_out, int out_size, void* d_ws, size_t ws_size,
                              hipStream_t stream) {
    const int*   species = (const int*)d_in[0];
    const float* coords  = (const float*)d_in[1];
    float*       out     = (float*)d_out;
    aev_kernel<<<NB * NA, 320, 0, stream>>>(species, coords, out);
}

// Round 5
// 66.030 us; speedup vs baseline: 1.5995x; 1.0069x over previous
//
#include <hip/hip_runtime.h>
#include <math.h>

#define NB 32
#define NA 48
#define RCRf 5.2f
#define RCAf 3.5f
#define PI_F 3.14159265358979f
#define TREC 1128   // >= C(47,2)=1081 worst-case triples -> always single chunk

typedef unsigned short ushort_t;
typedef __fp16 h2f __attribute__((ext_vector_type(2)));

static __device__ __forceinline__ unsigned pkh(float a, float b) {
    h2f v = __builtin_amdgcn_cvt_pkrtz(a, b);   // one v_cvt_pkrtz_f16_f32
    return __builtin_bit_cast(unsigned, v);
}
static __device__ __forceinline__ float uph(ushort_t u) {
    return (float)__builtin_bit_cast(__fp16, u);
}

// closed-form triangular decode: t -> (jj<kk) among m compacted neighbors
static __device__ __forceinline__ void tri_decode(int t, int m, int T, int& jj, int& kk) {
    const int u = T - 1 - t;
    int r = (int)((sqrtf(8.0f * (float)u + 1.0f) - 1.0f) * 0.5f);
    while (r * (r + 1) / 2 > u) --r;
    while ((r + 1) * (r + 2) / 2 <= u) ++r;
    jj = m - 2 - r;
    kk = m - 1 - (u - r * (r + 1) / 2);
}

// One block per (batch, center atom). 320 threads = 5 waves.
// vs R3: single chunk always (fp16 triple records fit T_max=1081 in ~27KB LDS),
// so every block runs exactly 5 barriers; pair vectors as float4 -> ds_read_b128.
// ~31 KB LDS -> 5 blocks/CU (25 waves/CU).
__global__ __launch_bounds__(320)
void aev_kernel(const int* __restrict__ species, const float* __restrict__ coords,
                float* __restrict__ out)
{
    const int bid = blockIdx.x;
    const int b = bid / NA;
    const int i = bid - b * NA;
    const int tid = threadIdx.x;

    __shared__ float crd[NA * 3];
    __shared__ int   ssp[NA];
    __shared__ float pd[NA], pfr[NA];
    __shared__ __align__(16) float4 cpk[NA];   // (dx,dy,dz,d) of compacted RCA neighbors
    __shared__ float cfc[NA];
    __shared__ int   csp[NA];
    __shared__ int   sm;
    __shared__ float radpart[5 * 64];
    __shared__ __align__(16) ushort_t f1h[TREC * 8];   // fp16 f1[z], 16 B/triple
    __shared__ __align__(16) ushort_t w2h[TREC * 4];   // fp16 w*f2[a], 8 B/triple
    __shared__ int   cnt[10];
    __shared__ unsigned cur[10];

    // ---- load batch coords + species, zero histogram ----
    if (tid < NA * 3) crd[tid] = coords[(size_t)b * NA * 3 + tid];
    if (tid >= 192 && tid < 192 + NA) ssp[tid - 192] = species[b * NA + (tid - 192)];
    if (tid >= 256 && tid < 266) cnt[tid - 256] = 0;
    __syncthreads();                                                  // S1

    const float xi = crd[3 * i], yi = crd[3 * i + 1], zi = crd[3 * i + 2];

    // ---- pair pass (wave 0): distances, radial fc, ballot-compacted RCA list ----
    if (tid < 64) {
        const int j = tid;
        float dx = 0.f, dy = 0.f, dz = 0.f, d = 1.0f, fr = 0.0f, fa = 0.0f;
        bool inA = false;
        if (j < NA) {
            dx = crd[3 * j] - xi; dy = crd[3 * j + 1] - yi; dz = crd[3 * j + 2] - zi;
            d = sqrtf(dx * dx + dy * dy + dz * dz);
            if (j != i && d <= RCRf) fr = 0.5f * __cosf((PI_F / RCRf) * d) + 0.5f;
            if (j != i && d <= RCAf) { inA = true; fa = 0.5f * __cosf((PI_F / RCAf) * d) + 0.5f; }
            pd[j] = d; pfr[j] = fr;
        }
        const unsigned long long mask = __ballot(inA);
        if (inA) {
            const int pos = (int)__popcll(mask & ((1ull << j) - 1ull));
            cpk[pos] = make_float4(dx, dy, dz, d);
            cfc[pos] = fa; csp[pos] = ssp[j];
        }
        if (j == 0) sm = (int)__popcll(mask);
    }
    __syncthreads();                                                  // S2

    const int m = sm;
    const int T = m * (m - 1) / 2;

    // ---- radial (register acc over broadcast LDS reads) ----
    {
        const int f = tid & 63, seg = tid >> 6;
        const int s = f >> 4, r = f & 15;
        const float shf = 0.9f + 0.26875f * (float)r;
        float acc = 0.0f;
        const int j0 = seg * 10, j1 = min(NA, j0 + 10);
        for (int j = j0; j < j1; ++j) {
            const float fr = pfr[j];
            if (fr != 0.0f) {
                const float u = pd[j] - shf;
                const float v = 0.25f * __expf(-16.0f * u * u) * fr;
                acc += (ssp[j] == s) ? v : 0.0f;
            }
        }
        radpart[seg * 64 + f] = acc;
    }
    // ---- histogram of pair indices ----
    for (int t = tid; t < T; t += 320) {
        int jj, kk; tri_decode(t, m, T, jj, kk);
        const int s1 = csp[jj], s2 = csp[kk];
        const int lo = min(s1, s2), hi = max(s1, s2);
        const int p = (lo * (9 - lo)) / 2 + (hi - lo);
        atomicAdd(&cnt[p], 1);
    }
    __syncthreads();                                                  // S3

    // ---- all-thread redundant prefix ----
    const int pmine = tid >> 5, amine = (tid >> 3) & 3, zmine = tid & 7;
    int mybase = 0, mycnt = 0, run = 0;
    #pragma unroll
    for (int p = 0; p < 10; ++p) {
        const int cp = cnt[p];
        if (p == pmine) { mybase = run; mycnt = cp; }
        if (tid < 10 && p == tid) cur[tid] = (unsigned)run;
        run += cp;
    }
    __syncthreads();                                                  // S4

    const float CZ[8] = { 0.98078528f, 0.83146961f, 0.55557023f, 0.19509032f,
                         -0.19509032f,-0.55557023f,-0.83146961f,-0.98078528f };
    const float SZ[8] = { 0.19509032f, 0.55557023f, 0.83146961f, 0.98078528f,
                          0.98078528f, 0.83146961f, 0.55557023f, 0.19509032f };
    const float SA[4] = { 0.9f, 1.55f, 2.2f, 2.85f };

    // ---- compute pass: fp16 records into p-sorted slots ----
    for (int t = tid; t < T; t += 320) {
        int jj, kk; tri_decode(t, m, T, jj, kk);
        const float4 qj = cpk[jj];      // ds_read_b128
        const float4 qk = cpk[kk];      // ds_read_b128
        const float dot = qj.x * qk.x + qj.y * qk.y + qj.z * qk.z;
        const float cosT = 0.95f * dot * __frcp_rn(qj.w * qk.w);
        const float sinT = sqrtf(fmaxf(1.0f - cosT * cosT, 0.0f));
        const float avg = 0.5f * (qj.w + qk.w);
        const float w = 2.0f * cfc[jj] * cfc[kk];
        const int s1 = csp[jj], s2 = csp[kk];
        const int lo = min(s1, s2), hi = max(s1, s2);
        const int p = (lo * (9 - lo)) / 2 + (hi - lo);

        float f1v[8];
        #pragma unroll
        for (int z = 0; z < 8; ++z) {
            const float base = 0.5f + 0.5f * (cosT * CZ[z] + sinT * SZ[z]);
            const float b2 = base * base, b4 = b2 * b2, b8 = b4 * b4, b16 = b8 * b8;
            f1v[z] = b16 * b16;   // base^32
        }
        float w2v[4];
        #pragma unroll
        for (int a = 0; a < 4; ++a) {
            const float u = avg - SA[a];
            w2v[a] = w * __expf(-8.0f * u * u);
        }
        const unsigned pos = atomicAdd(&cur[p], 1u);
        uint4 rf;
        rf.x = pkh(f1v[0], f1v[1]); rf.y = pkh(f1v[2], f1v[3]);
        rf.z = pkh(f1v[4], f1v[5]); rf.w = pkh(f1v[6], f1v[7]);
        ((uint4*)f1h)[pos] = rf;                       // ds_write_b128
        uint2 rw;
        rw.x = pkh(w2v[0], w2v[1]); rw.y = pkh(w2v[2], w2v[3]);
        ((uint2*)w2h)[pos] = rw;                       // ds_write_b64
    }
    __syncthreads();                                                  // S5

    // ---- reduce: each thread scans only its own p-bucket ----
    float acc_a = 0.0f;
    for (int k = mybase; k < mybase + mycnt; ++k)
        acc_a += uph(w2h[k * 4 + amine]) * uph(f1h[k * 8 + zmine]);

    // ---- output (radpart fenced by S3/S5; acc_a is a register) ----
    float* op = out + NB * NA + (size_t)(b * NA + i) * 384;
    if (tid < 64) {
        op[tid] = radpart[tid] + radpart[64 + tid] + radpart[128 + tid] +
                  radpart[192 + tid] + radpart[256 + tid];
    }
    op[64 + tid] = acc_a;
    if (tid == 0) out[b * NA + i] = (float)ssp[i];
}

extern "C" void kernel_launch(void* const* d_in, const int* in_sizes, int n_in,
                              void* d_out, int out_size, void* d_ws, size_t ws_size,
                              hipStream_t stream) {
    const int*   species = (const int*)d_in[0];
    const float* coords  = (const float*)d_in[1];
    float*       out     = (float*)d_out;
    aev_kernel<<<NB * NA, 320, 0, stream>>>(species, coords, out);
}